// Round 11
// baseline (1342.995 us; speedup 1.0000x reference)
//
#include <hip/hip_runtime.h>
#include <math.h>

#define BB 32
#define PP 32
#define NN 4096
#define DD 768
#define MM 4096
#define WROWS 64           // rows per update window
#define NWIN (NN / WROWS)  // 64 windows per b
#define SIMB 256           // n per ksim block
#define SKC 32             // k chunk in ksim
#define KCN (DD / SKC)     // 24 k-chunks
#define FPAD 40            // shorts per LDS row (32 + 8 pad, keeps b128 16B-aligned)

typedef __attribute__((ext_vector_type(8))) short short8v;
typedef __attribute__((ext_vector_type(4))) short short4v;
typedef __attribute__((ext_vector_type(4))) float float4v;

__device__ __forceinline__ float wsum(float v) {
    for (int o = 32; o > 0; o >>= 1) v += __shfl_down(v, o, 64);
    return v;
}
__device__ __forceinline__ float wmax(float v) {
    for (int o = 32; o > 0; o >>= 1) v = fmaxf(v, __shfl_down(v, o, 64));
    return v;
}
__device__ __forceinline__ unsigned short f2bf(float x) {  // RNE float->bf16
    unsigned u = __float_as_uint(x);
    return (unsigned short)((u + 0x7FFFu + ((u >> 16) & 1u)) >> 16);
}
__device__ __forceinline__ float bf2f(unsigned short h) {
    return __uint_as_float((unsigned)h << 16);
}

// ---- cosine-sim GEMM via bf16 MFMA, exact 4-term hi/lo split -------------
// grid: BB*16 blocks, 256 threads (4 waves); wave tile 16p x 128n.
// Raw-barrier pipeline: prefetch kc+1 issued after staging barrier, stays in
// flight across MFMA + barriers (no vmcnt(0) drain at barriers).
__global__ __launch_bounds__(256) void ksim(
    const float* __restrict__ prot, const float* __restrict__ feats,
    size_t fsb, float* __restrict__ out) {
    __shared__ short fsH[SIMB][FPAD];  // 20 KB feats hi
    __shared__ short fsL[SIMB][FPAD];  // 20 KB feats lo
    __shared__ short psH[PP][FPAD];    // 2.5 KB prot hi
    __shared__ short psL[PP][FPAD];    // 2.5 KB prot lo
    __shared__ float nfl[SIMB];
    __shared__ float pnl[PP];
    int bid = blockIdx.x;
    int b = bid >> 4, nt = bid & 15;
    int n0 = nt * SIMB;
    int tid = threadIdx.x;
    int row = tid >> 3, j = tid & 7;  // 8 threads per row
    int l = tid & 63, w = tid >> 6;
    int wp = w & 1, wn = w >> 1;
    const float* fb = feats + (size_t)b * fsb + (size_t)n0 * DD;
    const float* pb = prot + (size_t)b * (PP * DD);
    float4v acc[8] = {};
    float nacc[8] = {};
    float pacc = 0.f;
    float4 fv[8], pv;
#pragma unroll
    for (int ps = 0; ps < 8; ++ps)
        fv[ps] = *(const float4*)&fb[(size_t)(row + 32 * ps) * DD + j * 4];
    pv = *(const float4*)&pb[(size_t)row * DD + j * 4];
    for (int kc = 0; kc < KCN; ++kc) {
        __builtin_amdgcn_s_barrier();  // all waves done reading LDS
        asm volatile("" ::: "memory");
#pragma unroll
        for (int ps = 0; ps < 8; ++ps) {
            float4 v = fv[ps];
            nacc[ps] += v.x * v.x + v.y * v.y + v.z * v.z + v.w * v.w;
            short4v h, lo;
            h.x = (short)f2bf(v.x); h.y = (short)f2bf(v.y);
            h.z = (short)f2bf(v.z); h.w = (short)f2bf(v.w);
            lo.x = (short)f2bf(v.x - bf2f((unsigned short)h.x));
            lo.y = (short)f2bf(v.y - bf2f((unsigned short)h.y));
            lo.z = (short)f2bf(v.z - bf2f((unsigned short)h.z));
            lo.w = (short)f2bf(v.w - bf2f((unsigned short)h.w));
            *(short4v*)&fsH[row + 32 * ps][j * 4] = h;
            *(short4v*)&fsL[row + 32 * ps][j * 4] = lo;
        }
        {
            float4 v = pv;
            pacc += v.x * v.x + v.y * v.y + v.z * v.z + v.w * v.w;
            short4v h, lo;
            h.x = (short)f2bf(v.x); h.y = (short)f2bf(v.y);
            h.z = (short)f2bf(v.z); h.w = (short)f2bf(v.w);
            lo.x = (short)f2bf(v.x - bf2f((unsigned short)h.x));
            lo.y = (short)f2bf(v.y - bf2f((unsigned short)h.y));
            lo.z = (short)f2bf(v.z - bf2f((unsigned short)h.z));
            lo.w = (short)f2bf(v.w - bf2f((unsigned short)h.w));
            *(short4v*)&psH[row][j * 4] = h;
            *(short4v*)&psL[row][j * 4] = lo;
        }
        asm volatile("s_waitcnt lgkmcnt(0)" ::: "memory");  // own ds_writes done
        __builtin_amdgcn_s_barrier();                        // staging visible
        asm volatile("" ::: "memory");
        if (kc + 1 < KCN) {  // prefetch kc+1: in flight through MFMA + barriers
            int k0n = (kc + 1) * SKC;
#pragma unroll
            for (int ps = 0; ps < 8; ++ps)
                fv[ps] = *(const float4*)&fb[(size_t)(row + 32 * ps) * DD + k0n + j * 4];
            pv = *(const float4*)&pb[(size_t)row * DD + k0n + j * 4];
        }
        short8v ah = *(const short8v*)&psH[wp * 16 + (l & 15)][(l >> 4) * 8];
        short8v al = *(const short8v*)&psL[wp * 16 + (l & 15)][(l >> 4) * 8];
#pragma unroll
        for (int nf = 0; nf < 8; ++nf) {
            int nr = wn * 128 + nf * 16 + (l & 15);
            short8v bh = *(const short8v*)&fsH[nr][(l >> 4) * 8];
            short8v bl = *(const short8v*)&fsL[nr][(l >> 4) * 8];
            acc[nf] = __builtin_amdgcn_mfma_f32_16x16x32_bf16(ah, bh, acc[nf], 0, 0, 0);
            acc[nf] = __builtin_amdgcn_mfma_f32_16x16x32_bf16(ah, bl, acc[nf], 0, 0, 0);
            acc[nf] = __builtin_amdgcn_mfma_f32_16x16x32_bf16(al, bh, acc[nf], 0, 0, 0);
            acc[nf] = __builtin_amdgcn_mfma_f32_16x16x32_bf16(al, bl, acc[nf], 0, 0, 0);
        }
    }
    // norm reductions over 8-lane j-groups
#pragma unroll
    for (int ps = 0; ps < 8; ++ps) {
        float s = nacc[ps];
        s += __shfl_xor(s, 1, 64);
        s += __shfl_xor(s, 2, 64);
        s += __shfl_xor(s, 4, 64);
        if (j == 0) nfl[row + 32 * ps] = sqrtf(s);
    }
    {
        float s = pacc;
        s += __shfl_xor(s, 1, 64);
        s += __shfl_xor(s, 2, 64);
        s += __shfl_xor(s, 4, 64);
        if (j == 0) pnl[row] = sqrtf(s);
    }
    __syncthreads();
#pragma unroll
    for (int nf = 0; nf < 8; ++nf) {
        int nr = wn * 128 + nf * 16 + (l & 15);
        float fn = nfl[nr];
#pragma unroll
        for (int r = 0; r < 4; ++r) {
            int p = wp * 16 + (l >> 4) * 4 + r;
            float dnm = fmaxf(pnl[p] * fn, 1e-8f);
            out[(size_t)(b * PP + p) * NN + n0 + nr] = acc[nf][r] / dnm;
        }
    }
}

// ---- fused assign: stats (density->tau, max, Z) + argmax + counting sort -
// one block per b, 1024 threads = 16 waves. EXACT round-9 weight formula —
// the per-(n,p) comparison expression expf(s/tt-xm)/Z must not be reordered
// (round-10 log-space reformulation flipped near-tie argmaxes and failed).
__global__ __launch_bounds__(1024) void kassign(const float* __restrict__ sim,
                                                int* __restrict__ sortn,
                                                float* __restrict__ sortw,
                                                int* __restrict__ cnt,
                                                int* __restrict__ offs,
                                                int hasPrev) {
    __shared__ float swv[NN];            // 16 KB weights
    __shared__ unsigned char sidx[NN];   // 4 KB argmax idx
    __shared__ int cntc[64][PP];         // 8 KB per-chunk per-p counts -> bases
    __shared__ float ttl[PP], xml[PP], zrl[PP];
    __shared__ int offp[PP], totl[PP];
    int b = blockIdx.x;
    int tid = threadIdx.x;
    int w = tid >> 6, lane = tid & 63;
    const float* sb = sim + (size_t)(b * PP) * NN;

    // phase 1: per-row stats; wave w handles rows p = w, w+16
    for (int p = w; p < PP; p += 16) {
        const float4* r4 = (const float4*)(sb + (size_t)p * NN);
        float mx = -3.4e38f;
        for (int q = 0; q < 16; ++q) {
            float4 x = r4[lane + 64 * q];
            mx = fmaxf(mx, fmaxf(fmaxf(x.x, x.y), fmaxf(x.z, x.w)));
        }
        float bm = wmax(mx);
        bm = __shfl(bm, 0, 64);
        float ttv;
        if (hasPrev) {
            int bp = b * PP + p;
            int c = cnt[bp];
            const int* lp = sortn + (size_t)b * NN + offs[bp];
            float s = 0.f;
            for (int jj = lane; jj < c; jj += 64) s += sb[(size_t)p * NN + (lp[jj] & 0xFFF)];
            float sm = wsum(s);
            sm = __shfl(sm, 0, 64);
            float density = (c >= 1) ? (1.f - sm / (float)c) : 1.f;
            ttv = 0.1f * fmaxf(density, 1e-10f);
        } else {
            ttv = 0.01f;  // TEMP * TAU0
        }
        float xm = bm / ttv;
        float z = 0.f;
        for (int q = 0; q < 16; ++q) {
            float4 x = r4[lane + 64 * q];
            z += expf(x.x / ttv - xm) + expf(x.y / ttv - xm) +
                 expf(x.z / ttv - xm) + expf(x.w / ttv - xm);
        }
        float zz = wsum(z);
        if (lane == 0) { ttl[p] = ttv; xml[p] = xm; zrl[p] = zz; }
    }
    __syncthreads();

    // phase 2: per-n argmax + per-chunk counts (exact round-9 arithmetic)
    for (int ci = 0; ci < 4; ++ci) {
        int c = w + 16 * ci;
        int n = c * 64 + lane;
        float best = -1.f;
        int bi = 0;
#pragma unroll
        for (int p = 0; p < PP; ++p) {
            float s = sb[(size_t)p * NN + n];
            float wgt = expf(s / ttl[p] - xml[p]) / zrl[p];
            if (wgt > best) { best = wgt; bi = p; }
        }
        sidx[n] = (unsigned char)bi;
        swv[n] = best;
#pragma unroll
        for (int p = 0; p < PP; ++p) {
            unsigned long long bal = __ballot(bi == p);
            if (lane == p) cntc[c][p] = __popcll(bal);
        }
    }
    __syncthreads();

    // phase 3: per-p prefix over chunks, then exclusive prefix over p
    if (tid < PP) {
        int run = 0;
        for (int c = 0; c < 64; ++c) {
            int t_ = cntc[c][tid];
            cntc[c][tid] = run;
            run += t_;
        }
        totl[tid] = run;
        cnt[b * PP + tid] = run;
    }
    __syncthreads();
    if (tid == 0) {
        int s = 0;
        for (int p = 0; p < PP; ++p) {
            offp[p] = s;
            offs[b * PP + p] = s;
            s += totl[p];
        }
    }
    __syncthreads();

    // phase 4: stable scatter (ascending n within bucket)
    for (int ci = 0; ci < 4; ++ci) {
        int c = w + 16 * ci;
        int n = c * 64 + lane;
        int bi = sidx[n];
        float wgt = swv[n];
        unsigned long long below = (1ull << lane) - 1ull;
#pragma unroll
        for (int p = 0; p < PP; ++p) {
            unsigned long long bal = __ballot(bi == p);
            if (bi == p) {
                int rank = __popcll(bal & below);
                int pos = offp[p] + cntc[c][p] + rank;
                sortn[(size_t)b * NN + pos] = (p << 12) | n;
                sortw[(size_t)b * NN + pos] = wgt;
            }
        }
    }
}

// ---- update: 64-row window, float4 gather with 8-deep register prefetch --
#define UPD_STEP(FREG, JIDX, NXT)                                          \
    {                                                                      \
        int e = sn[JIDX];                                                  \
        int p = e >> 12;                                                   \
        float wv = sw[JIDX];                                               \
        float4 f = FREG;                                                   \
        if ((NXT) < WROWS) FREG = fb[(size_t)(sn[NXT] & 0xFFF) * 192 + t]; \
        if (p != curp) {                                                   \
            float4 o = {ax, ay, az, aw};                                   \
            pw[(size_t)curp * 192 + t] = o;                                \
            ax = ay = az = aw = 0.f;                                       \
            curp = p;                                                      \
        }                                                                  \
        ax = fmaf(wv, f.x, ax);                                            \
        ay = fmaf(wv, f.y, ay);                                            \
        az = fmaf(wv, f.z, az);                                            \
        aw = fmaf(wv, f.w, aw);                                            \
    }

__global__ __launch_bounds__(192) void kupdate(const float* __restrict__ feats,
                                               const int* __restrict__ sortn,
                                               const float* __restrict__ sortw,
                                               float* __restrict__ part) {
    __shared__ int sn[WROWS];
    __shared__ float sw[WROWS];
    int win = blockIdx.x & (NWIN - 1);
    int b = blockIdx.x >> 6;
    int t = threadIdx.x;
    if (t < WROWS) {
        sn[t] = sortn[b * NN + win * WROWS + t];
        sw[t] = sortw[b * NN + win * WROWS + t];
    }
    __syncthreads();
    const float4* fb = (const float4*)(feats + (size_t)b * NN * DD);
    float4* pw = (float4*)(part + (size_t)(b * NWIN + win) * PP * DD);
    float ax = 0.f, ay = 0.f, az = 0.f, aw = 0.f;
    int curp = sn[0] >> 12;
    float4 fp0 = fb[(size_t)(sn[0] & 0xFFF) * 192 + t];
    float4 fp1 = fb[(size_t)(sn[1] & 0xFFF) * 192 + t];
    float4 fp2 = fb[(size_t)(sn[2] & 0xFFF) * 192 + t];
    float4 fp3 = fb[(size_t)(sn[3] & 0xFFF) * 192 + t];
    float4 fp4 = fb[(size_t)(sn[4] & 0xFFF) * 192 + t];
    float4 fp5 = fb[(size_t)(sn[5] & 0xFFF) * 192 + t];
    float4 fp6 = fb[(size_t)(sn[6] & 0xFFF) * 192 + t];
    float4 fp7 = fb[(size_t)(sn[7] & 0xFFF) * 192 + t];
    for (int jj = 0; jj < WROWS; jj += 8) {
        UPD_STEP(fp0, jj + 0, jj + 8);
        UPD_STEP(fp1, jj + 1, jj + 9);
        UPD_STEP(fp2, jj + 2, jj + 10);
        UPD_STEP(fp3, jj + 3, jj + 11);
        UPD_STEP(fp4, jj + 4, jj + 12);
        UPD_STEP(fp5, jj + 5, jj + 13);
        UPD_STEP(fp6, jj + 6, jj + 14);
        UPD_STEP(fp7, jj + 7, jj + 15);
    }
    float4 o = {ax, ay, az, aw};
    pw[(size_t)curp * 192 + t] = o;
}

// ---- reduce window partials -> prototypes (+ final out) ------------------
__global__ __launch_bounds__(192) void kreduce(const float* __restrict__ part,
                                               const int* __restrict__ offs,
                                               const int* __restrict__ cnt,
                                               float* __restrict__ prot,
                                               float* __restrict__ outp) {
    int bp = blockIdx.x;
    int b = bp >> 5, p = bp & 31;
    int t = threadIdx.x;
    float4 s = {0.f, 0.f, 0.f, 0.f};
    int c = cnt[bp];
    if (c > 0) {
        int j0 = offs[bp];
        int w0 = j0 >> 6, w1 = (j0 + c - 1) >> 6;
        const float4* pr = (const float4*)(part);
        for (int w = w0; w <= w1; ++w) {
            float4 v = pr[(size_t)((b * NWIN + w) * PP + p) * 192 + t];
            s.x += v.x; s.y += v.y; s.z += v.z; s.w += v.w;
        }
    }
    ((float4*)(prot + (size_t)bp * DD))[t] = s;
    if (outp) ((float4*)(outp + (size_t)bp * DD))[t] = s;
}

extern "C" void kernel_launch(void* const* d_in, const int* in_sizes, int n_in,
                              void* d_out, int out_size, void* d_ws, size_t ws_size,
                              hipStream_t stream) {
    const float* protIn = (const float*)d_in[0];
    const float* feats = (const float*)d_in[1];
    const float* forg = (const float*)d_in[2];
    float* out = (float*)d_out;

    char* w = (char*)d_ws;
    auto alloc = [&](size_t bytes) {
        char* p = w;
        w += (bytes + 255) & ~(size_t)255;
        return p;
    };
    float* sim = (float*)alloc((size_t)BB * PP * NN * 4);
    float* prot = (float*)alloc((size_t)BB * PP * DD * 4);
    float* part = (float*)alloc((size_t)BB * NWIN * PP * DD * 4);
    int* sortn = (int*)alloc((size_t)BB * NN * 4);
    float* sortw = (float*)alloc((size_t)BB * NN * 4);
    int* cnt = (int*)alloc(BB * PP * 4);
    int* offs = (int*)alloc(BB * PP * 4);

    for (int t = 0; t < 5; ++t) {
        ksim<<<BB * 16, 256, 0, stream>>>(t == 0 ? protIn : prot, feats,
                                          (size_t)NN * DD, sim);
        kassign<<<BB, 1024, 0, stream>>>(sim, sortn, sortw, cnt, offs, t > 0 ? 1 : 0);
        kupdate<<<BB * NWIN, 192, 0, stream>>>(feats, sortn, sortw, part);
        kreduce<<<BB * PP, 192, 0, stream>>>(part, offs, cnt, prot,
                                             (t == 4) ? out : nullptr);
    }
    // final similarity against feats_org (broadcast fsb=0) -> second output
    ksim<<<BB * 16, 256, 0, stream>>>(prot, forg, (size_t)0,
                                      out + (size_t)BB * PP * DD);
}

// Round 12
// 1298.800 us; speedup vs baseline: 1.0340x; 1.0340x over previous
//
#include <hip/hip_runtime.h>
#include <math.h>

#define BB 32
#define PP 32
#define NN 4096
#define DD 768
#define MM 4096
#define WROWS 64           // rows per update window
#define NWIN (NN / WROWS)  // 64 windows per b
#define SIMB 128           // n per ksim block (128 -> 1024 blocks, 4/CU)
#define SNT (NN / SIMB)    // 32 n-tiles
#define SKC 32             // k chunk in ksim
#define KCN (DD / SKC)     // 24 k-chunks
#define FPAD 40            // shorts per LDS row (32 + 8 pad, keeps b128 16B-aligned)

typedef __attribute__((ext_vector_type(8))) short short8v;
typedef __attribute__((ext_vector_type(4))) short short4v;
typedef __attribute__((ext_vector_type(4))) float float4v;

__device__ __forceinline__ float wsum(float v) {
    for (int o = 32; o > 0; o >>= 1) v += __shfl_down(v, o, 64);
    return v;
}
__device__ __forceinline__ float wmax(float v) {
    for (int o = 32; o > 0; o >>= 1) v = fmaxf(v, __shfl_down(v, o, 64));
    return v;
}
__device__ __forceinline__ unsigned short f2bf(float x) {  // RNE float->bf16
    unsigned u = __float_as_uint(x);
    return (unsigned short)((u + 0x7FFFu + ((u >> 16) & 1u)) >> 16);
}
__device__ __forceinline__ float bf2f(unsigned short h) {
    return __uint_as_float((unsigned)h << 16);
}

// ---- cosine-sim GEMM via bf16 MFMA, exact 4-term hi/lo split -------------
// grid: BB*SNT blocks, 256 threads (4 waves); wave tile 16p x 64n.
// Raw-barrier pipeline: prefetch kc+1 issued after staging barrier, stays in
// flight across MFMA + barriers (no vmcnt(0) drain at barriers).
__global__ __launch_bounds__(256) void ksim(
    const float* __restrict__ prot, const float* __restrict__ feats,
    size_t fsb, float* __restrict__ out) {
    __shared__ short fsH[SIMB][FPAD];  // 10 KB feats hi
    __shared__ short fsL[SIMB][FPAD];  // 10 KB feats lo
    __shared__ short psH[PP][FPAD];    // 2.5 KB prot hi
    __shared__ short psL[PP][FPAD];    // 2.5 KB prot lo
    __shared__ float nfl[SIMB];
    __shared__ float pnl[PP];
    int bid = blockIdx.x;
    int b = bid >> 5, nt = bid & 31;
    int n0 = nt * SIMB;
    int tid = threadIdx.x;
    int row = tid >> 3, j = tid & 7;  // 8 threads per row (32 rows/pass)
    int l = tid & 63, w = tid >> 6;
    int wp = w & 1, wn = w >> 1;      // wave tile: 16p x 64n
    const float* fb = feats + (size_t)b * fsb + (size_t)n0 * DD;
    const float* pb = prot + (size_t)b * (PP * DD);
    float4v acc[4] = {};
    float nacc[4] = {};
    float pacc = 0.f;
    float4 fv[4], pv;
#pragma unroll
    for (int ps = 0; ps < 4; ++ps)
        fv[ps] = *(const float4*)&fb[(size_t)(row + 32 * ps) * DD + j * 4];
    pv = *(const float4*)&pb[(size_t)row * DD + j * 4];
    for (int kc = 0; kc < KCN; ++kc) {
        __builtin_amdgcn_s_barrier();  // all waves done reading LDS
        asm volatile("" ::: "memory");
#pragma unroll
        for (int ps = 0; ps < 4; ++ps) {
            float4 v = fv[ps];
            nacc[ps] += v.x * v.x + v.y * v.y + v.z * v.z + v.w * v.w;
            short4v h, lo;
            h.x = (short)f2bf(v.x); h.y = (short)f2bf(v.y);
            h.z = (short)f2bf(v.z); h.w = (short)f2bf(v.w);
            lo.x = (short)f2bf(v.x - bf2f((unsigned short)h.x));
            lo.y = (short)f2bf(v.y - bf2f((unsigned short)h.y));
            lo.z = (short)f2bf(v.z - bf2f((unsigned short)h.z));
            lo.w = (short)f2bf(v.w - bf2f((unsigned short)h.w));
            *(short4v*)&fsH[row + 32 * ps][j * 4] = h;
            *(short4v*)&fsL[row + 32 * ps][j * 4] = lo;
        }
        {
            float4 v = pv;
            pacc += v.x * v.x + v.y * v.y + v.z * v.z + v.w * v.w;
            short4v h, lo;
            h.x = (short)f2bf(v.x); h.y = (short)f2bf(v.y);
            h.z = (short)f2bf(v.z); h.w = (short)f2bf(v.w);
            lo.x = (short)f2bf(v.x - bf2f((unsigned short)h.x));
            lo.y = (short)f2bf(v.y - bf2f((unsigned short)h.y));
            lo.z = (short)f2bf(v.z - bf2f((unsigned short)h.z));
            lo.w = (short)f2bf(v.w - bf2f((unsigned short)h.w));
            *(short4v*)&psH[row][j * 4] = h;
            *(short4v*)&psL[row][j * 4] = lo;
        }
        asm volatile("s_waitcnt lgkmcnt(0)" ::: "memory");  // own ds_writes done
        __builtin_amdgcn_s_barrier();                        // staging visible
        asm volatile("" ::: "memory");
        if (kc + 1 < KCN) {  // prefetch kc+1: in flight through MFMA + barriers
            int k0n = (kc + 1) * SKC;
#pragma unroll
            for (int ps = 0; ps < 4; ++ps)
                fv[ps] = *(const float4*)&fb[(size_t)(row + 32 * ps) * DD + k0n + j * 4];
            pv = *(const float4*)&pb[(size_t)row * DD + k0n + j * 4];
        }
        short8v ah = *(const short8v*)&psH[wp * 16 + (l & 15)][(l >> 4) * 8];
        short8v al = *(const short8v*)&psL[wp * 16 + (l & 15)][(l >> 4) * 8];
#pragma unroll
        for (int nf = 0; nf < 4; ++nf) {
            int nr = wn * 64 + nf * 16 + (l & 15);
            short8v bh = *(const short8v*)&fsH[nr][(l >> 4) * 8];
            short8v bl = *(const short8v*)&fsL[nr][(l >> 4) * 8];
            acc[nf] = __builtin_amdgcn_mfma_f32_16x16x32_bf16(ah, bh, acc[nf], 0, 0, 0);
            acc[nf] = __builtin_amdgcn_mfma_f32_16x16x32_bf16(ah, bl, acc[nf], 0, 0, 0);
            acc[nf] = __builtin_amdgcn_mfma_f32_16x16x32_bf16(al, bh, acc[nf], 0, 0, 0);
            acc[nf] = __builtin_amdgcn_mfma_f32_16x16x32_bf16(al, bl, acc[nf], 0, 0, 0);
        }
    }
    // norm reductions over 8-lane j-groups
#pragma unroll
    for (int ps = 0; ps < 4; ++ps) {
        float s = nacc[ps];
        s += __shfl_xor(s, 1, 64);
        s += __shfl_xor(s, 2, 64);
        s += __shfl_xor(s, 4, 64);
        if (j == 0) nfl[row + 32 * ps] = sqrtf(s);
    }
    {
        float s = pacc;
        s += __shfl_xor(s, 1, 64);
        s += __shfl_xor(s, 2, 64);
        s += __shfl_xor(s, 4, 64);
        if (j == 0) pnl[row] = sqrtf(s);
    }
    __syncthreads();
#pragma unroll
    for (int nf = 0; nf < 4; ++nf) {
        int nr = wn * 64 + nf * 16 + (l & 15);
        float fn = nfl[nr];
#pragma unroll
        for (int r = 0; r < 4; ++r) {
            int p = wp * 16 + (l >> 4) * 4 + r;
            float dnm = fmaxf(pnl[p] * fn, 1e-8f);
            out[(size_t)(b * PP + p) * NN + n0 + nr] = acc[nf][r] / dnm;
        }
    }
}

// ---- fused assign: stats (density->tau, max, Z) + argmax + counting sort -
// one block per b, 1024 threads = 16 waves. EXACT round-9 weight formula —
// the per-(n,p) comparison expression expf(s/tt-xm)/Z must not be reordered
// (round-10 log-space reformulation flipped near-tie argmaxes and failed).
__global__ __launch_bounds__(1024) void kassign(const float* __restrict__ sim,
                                                int* __restrict__ sortn,
                                                float* __restrict__ sortw,
                                                int* __restrict__ cnt,
                                                int* __restrict__ offs,
                                                int hasPrev) {
    __shared__ float swv[NN];            // 16 KB weights
    __shared__ unsigned char sidx[NN];   // 4 KB argmax idx
    __shared__ int cntc[64][PP];         // 8 KB per-chunk per-p counts -> bases
    __shared__ float ttl[PP], xml[PP], zrl[PP];
    __shared__ int offp[PP], totl[PP];
    int b = blockIdx.x;
    int tid = threadIdx.x;
    int w = tid >> 6, lane = tid & 63;
    const float* sb = sim + (size_t)(b * PP) * NN;

    // phase 1: per-row stats; wave w handles rows p = w, w+16
    for (int p = w; p < PP; p += 16) {
        const float4* r4 = (const float4*)(sb + (size_t)p * NN);
        float mx = -3.4e38f;
        for (int q = 0; q < 16; ++q) {
            float4 x = r4[lane + 64 * q];
            mx = fmaxf(mx, fmaxf(fmaxf(x.x, x.y), fmaxf(x.z, x.w)));
        }
        float bm = wmax(mx);
        bm = __shfl(bm, 0, 64);
        float ttv;
        if (hasPrev) {
            int bp = b * PP + p;
            int c = cnt[bp];
            const int* lp = sortn + (size_t)b * NN + offs[bp];
            float s = 0.f;
            for (int jj = lane; jj < c; jj += 64) s += sb[(size_t)p * NN + (lp[jj] & 0xFFF)];
            float sm = wsum(s);
            sm = __shfl(sm, 0, 64);
            float density = (c >= 1) ? (1.f - sm / (float)c) : 1.f;
            ttv = 0.1f * fmaxf(density, 1e-10f);
        } else {
            ttv = 0.01f;  // TEMP * TAU0
        }
        float xm = bm / ttv;
        float z = 0.f;
        for (int q = 0; q < 16; ++q) {
            float4 x = r4[lane + 64 * q];
            z += expf(x.x / ttv - xm) + expf(x.y / ttv - xm) +
                 expf(x.z / ttv - xm) + expf(x.w / ttv - xm);
        }
        float zz = wsum(z);
        if (lane == 0) { ttl[p] = ttv; xml[p] = xm; zrl[p] = zz; }
    }
    __syncthreads();

    // phase 2: per-n argmax + per-chunk counts (exact round-9 arithmetic)
    for (int ci = 0; ci < 4; ++ci) {
        int c = w + 16 * ci;
        int n = c * 64 + lane;
        float best = -1.f;
        int bi = 0;
#pragma unroll
        for (int p = 0; p < PP; ++p) {
            float s = sb[(size_t)p * NN + n];
            float wgt = expf(s / ttl[p] - xml[p]) / zrl[p];
            if (wgt > best) { best = wgt; bi = p; }
        }
        sidx[n] = (unsigned char)bi;
        swv[n] = best;
#pragma unroll
        for (int p = 0; p < PP; ++p) {
            unsigned long long bal = __ballot(bi == p);
            if (lane == p) cntc[c][p] = __popcll(bal);
        }
    }
    __syncthreads();

    // phase 3: per-p prefix over chunks, then exclusive prefix over p
    if (tid < PP) {
        int run = 0;
        for (int c = 0; c < 64; ++c) {
            int t_ = cntc[c][tid];
            cntc[c][tid] = run;
            run += t_;
        }
        totl[tid] = run;
        cnt[b * PP + tid] = run;
    }
    __syncthreads();
    if (tid == 0) {
        int s = 0;
        for (int p = 0; p < PP; ++p) {
            offp[p] = s;
            offs[b * PP + p] = s;
            s += totl[p];
        }
    }
    __syncthreads();

    // phase 4: stable scatter (ascending n within bucket)
    for (int ci = 0; ci < 4; ++ci) {
        int c = w + 16 * ci;
        int n = c * 64 + lane;
        int bi = sidx[n];
        float wgt = swv[n];
        unsigned long long below = (1ull << lane) - 1ull;
#pragma unroll
        for (int p = 0; p < PP; ++p) {
            unsigned long long bal = __ballot(bi == p);
            if (bi == p) {
                int rank = __popcll(bal & below);
                int pos = offp[p] + cntc[c][p] + rank;
                sortn[(size_t)b * NN + pos] = (p << 12) | n;
                sortw[(size_t)b * NN + pos] = wgt;
            }
        }
    }
}

// ---- update: 64-row window, float4 gather with 4-deep register prefetch --
#define UPD_STEP(FREG, JIDX, NXT)                                          \
    {                                                                      \
        int e = sn[JIDX];                                                  \
        int p = e >> 12;                                                   \
        float wv = sw[JIDX];                                               \
        float4 f = FREG;                                                   \
        if ((NXT) < WROWS) FREG = fb[(size_t)(sn[NXT] & 0xFFF) * 192 + t]; \
        if (p != curp) {                                                   \
            float4 o = {ax, ay, az, aw};                                   \
            pw[(size_t)curp * 192 + t] = o;                                \
            ax = ay = az = aw = 0.f;                                       \
            curp = p;                                                      \
        }                                                                  \
        ax = fmaf(wv, f.x, ax);                                            \
        ay = fmaf(wv, f.y, ay);                                            \
        az = fmaf(wv, f.z, az);                                            \
        aw = fmaf(wv, f.w, aw);                                            \
    }

__global__ __launch_bounds__(192) void kupdate(const float* __restrict__ feats,
                                               const int* __restrict__ sortn,
                                               const float* __restrict__ sortw,
                                               float* __restrict__ part) {
    __shared__ int sn[WROWS];
    __shared__ float sw[WROWS];
    int win = blockIdx.x & (NWIN - 1);
    int b = blockIdx.x >> 6;
    int t = threadIdx.x;
    if (t < WROWS) {
        sn[t] = sortn[b * NN + win * WROWS + t];
        sw[t] = sortw[b * NN + win * WROWS + t];
    }
    __syncthreads();
    const float4* fb = (const float4*)(feats + (size_t)b * NN * DD);
    float4* pw = (float4*)(part + (size_t)(b * NWIN + win) * PP * DD);
    float ax = 0.f, ay = 0.f, az = 0.f, aw = 0.f;
    int curp = sn[0] >> 12;
    float4 fp0 = fb[(size_t)(sn[0] & 0xFFF) * 192 + t];
    float4 fp1 = fb[(size_t)(sn[1] & 0xFFF) * 192 + t];
    float4 fp2 = fb[(size_t)(sn[2] & 0xFFF) * 192 + t];
    float4 fp3 = fb[(size_t)(sn[3] & 0xFFF) * 192 + t];
    for (int jj = 0; jj < WROWS; jj += 4) {
        UPD_STEP(fp0, jj + 0, jj + 4);
        UPD_STEP(fp1, jj + 1, jj + 5);
        UPD_STEP(fp2, jj + 2, jj + 6);
        UPD_STEP(fp3, jj + 3, jj + 7);
    }
    float4 o = {ax, ay, az, aw};
    pw[(size_t)curp * 192 + t] = o;
}

// ---- reduce window partials -> prototypes (+ final out) ------------------
__global__ __launch_bounds__(192) void kreduce(const float* __restrict__ part,
                                               const int* __restrict__ offs,
                                               const int* __restrict__ cnt,
                                               float* __restrict__ prot,
                                               float* __restrict__ outp) {
    int bp = blockIdx.x;
    int b = bp >> 5, p = bp & 31;
    int t = threadIdx.x;
    float4 s = {0.f, 0.f, 0.f, 0.f};
    int c = cnt[bp];
    if (c > 0) {
        int j0 = offs[bp];
        int w0 = j0 >> 6, w1 = (j0 + c - 1) >> 6;
        const float4* pr = (const float4*)(part);
        for (int w = w0; w <= w1; ++w) {
            float4 v = pr[(size_t)((b * NWIN + w) * PP + p) * 192 + t];
            s.x += v.x; s.y += v.y; s.z += v.z; s.w += v.w;
        }
    }
    ((float4*)(prot + (size_t)bp * DD))[t] = s;
    if (outp) ((float4*)(outp + (size_t)bp * DD))[t] = s;
}

extern "C" void kernel_launch(void* const* d_in, const int* in_sizes, int n_in,
                              void* d_out, int out_size, void* d_ws, size_t ws_size,
                              hipStream_t stream) {
    const float* protIn = (const float*)d_in[0];
    const float* feats = (const float*)d_in[1];
    const float* forg = (const float*)d_in[2];
    float* out = (float*)d_out;

    char* w = (char*)d_ws;
    auto alloc = [&](size_t bytes) {
        char* p = w;
        w += (bytes + 255) & ~(size_t)255;
        return p;
    };
    float* sim = (float*)alloc((size_t)BB * PP * NN * 4);
    float* prot = (float*)alloc((size_t)BB * PP * DD * 4);
    float* part = (float*)alloc((size_t)BB * NWIN * PP * DD * 4);
    int* sortn = (int*)alloc((size_t)BB * NN * 4);
    float* sortw = (float*)alloc((size_t)BB * NN * 4);
    int* cnt = (int*)alloc(BB * PP * 4);
    int* offs = (int*)alloc(BB * PP * 4);

    for (int t = 0; t < 5; ++t) {
        ksim<<<BB * SNT, 256, 0, stream>>>(t == 0 ? protIn : prot, feats,
                                           (size_t)NN * DD, sim);
        kassign<<<BB, 1024, 0, stream>>>(sim, sortn, sortw, cnt, offs, t > 0 ? 1 : 0);
        kupdate<<<BB * NWIN, 192, 0, stream>>>(feats, sortn, sortw, part);
        kreduce<<<BB * PP, 192, 0, stream>>>(part, offs, cnt, prot,
                                             (t == 4) ? out : nullptr);
    }
    // final similarity against feats_org (broadcast fsb=0) -> second output
    ksim<<<BB * SNT, 256, 0, stream>>>(prot, forg, (size_t)0,
                                       out + (size_t)BB * PP * DD);
}